// Round 1
// 320.386 us; speedup vs baseline: 1.0921x; 1.0921x over previous
//
#include <hip/hip_runtime.h>
#include <hip/hip_bf16.h>
#include <cstdint>
#include <cstddef>

// Problem constants
#define MROWS 8192   // B*L
#define EDIM  1024   // E
#define VDIM  64     // V
#define NTRI  2016   // V*(V-1)/2
#define NTC   2176   // NTRI + 64 (theta logits) padded to 17*128 tiles

typedef _Float16 half8  __attribute__((ext_vector_type(8)));
typedef _Float16 half4v __attribute__((ext_vector_type(4)));
typedef float    floatx4 __attribute__((ext_vector_type(4)));

typedef __attribute__((address_space(1))) void gvoid;
typedef __attribute__((address_space(3))) void svoid;

__device__ inline void gld_lds16(const _Float16* g, _Float16* l) {
    // async global->LDS, 16B per lane; LDS dest = wave-uniform base + lane*16
    __builtin_amdgcn_global_load_lds((gvoid*)g, (svoid*)l, 16, 0, 0);
}

// Fast erf: Abramowitz-Stegun 7.1.26, |err| < 1.5e-7 (hw v_exp_f32)
__device__ inline float fast_erf(float x) {
    float ax = fabsf(x);
    float t = 1.0f / (1.0f + 0.3275911f * ax);
    float p = t * (0.254829592f +
              t * (-0.284496736f +
              t * (1.421413741f +
              t * (-1.453152027f +
              t * 1.061405429f))));
    float r = 1.0f - p * __expf(-ax * ax);
    return copysignf(r, x);
}

// Fast softplus via hw v_exp/v_log; exact identity, stable both tails
__device__ inline float fast_softplus(float x) {
    return fmaxf(x, 0.0f) + __logf(1.0f + __expf(-fabsf(x)));
}

// ---------------- cast fp32 -> fp16 (with zero padding) ----------------
__global__ __launch_bounds__(256) void cast_f2h(const float* __restrict__ in,
                                                _Float16* __restrict__ out,
                                                int n_valid, int n_total) {
    int idx = (blockIdx.x * 256 + threadIdx.x) * 4;
    if (idx >= n_total) return;
    half4v o;
    if (idx < n_valid) {
        float4 v = *(const float4*)(in + idx);
        o[0] = (_Float16)v.x; o[1] = (_Float16)v.y;
        o[2] = (_Float16)v.z; o[3] = (_Float16)v.w;
    } else {
        o[0] = (_Float16)0.f; o[1] = (_Float16)0.f;
        o[2] = (_Float16)0.f; o[3] = (_Float16)0.f;
    }
    *(half4v*)(out + idx) = o;
}

// ---------------- GEMM: C = epilogue(A @ Bt^T), fp16 output ----------------
// A: M x K fp16 row-major, Bt: N x K fp16 row-major (i.e. B transposed)
// 128x128 tile per block, 256 threads (4 waves, 2x2 of 64x64), K-chunk 64.
//
// XCD-aware grid: 1D launch; block b -> xcd = b&7 (HW round-robin), and
// m-tile = xcd + 8*(slot/ntiles_n). All n-blocks of one m-tile run on the
// same XCD -> A-tile fetched from HBM once, then L2-hit.
//
// LDS: rows of 64 halfs (128 B). Slot (r, c) (c = 16B chunk 0..7) holds
// global chunk (c ^ (r&7)); staging permutes the global source within each
// row's 128 B line (global_load_lds LDS dest is lane-order-pinned);
// fragment reads invert -> every 16-lane ds_read_b128 phase is 2-way (free).
//
// MODE 0: gelu(x + bias[gn])                  (dense layer) -> fp16
// MODE 1: gn <  NTRI       -> softplus(x + bias[gn])   (Theta)    -> fp16
//         NTRI <= gn < +64 -> x + bias2[gn-NTRI]       (pi logits, raw)
//         else             -> 0                        (padding)
template <int MODE>
__global__ __launch_bounds__(256) void gemm_bt(const _Float16* __restrict__ A,
                                               const _Float16* __restrict__ Bt,
                                               const float* __restrict__ bias,
                                               const float* __restrict__ bias2,
                                               _Float16* __restrict__ C, int N) {
    __shared__ __align__(16) _Float16 As[128 * 64];
    __shared__ __align__(16) _Float16 Bs[128 * 64];

    const int tid  = threadIdx.x;
    // XCD-aware tile mapping
    const int ng   = N >> 7;             // n-tiles (17 or 8)
    const int xcd  = blockIdx.x & 7;
    const int slot = blockIdx.x >> 3;
    const int mg   = slot / ng;
    const int nn   = slot - mg * ng;
    const int m0   = (xcd + mg * 8) * 128;
    const int n0   = nn * 128;

    const int w    = tid >> 6;
    const int lane = tid & 63;
    const int wr   = w >> 1;             // wave row (0..1) -> 64 rows
    const int wc   = w & 1;              // wave col (0..1) -> 64 cols
    const int lrow  = lane & 15;         // m (A) / n (B) within 16
    const int lquad = lane >> 4;         // k-group (8 elems each)

    floatx4 acc[4][4] = {};

    // staging: thread t -> tile row r0 = t>>3 (+32 per call), chunk c0 = t&7.
    // LDS dest (pinned) = slot (r0, c0); global source chunk g = c0 ^ (r0&7).
    const int r0 = tid >> 3;             // 0..31
    const int c0 = tid & 7;
    const int g  = (c0 ^ (r0 & 7)) * 8;  // halfs offset within row's 64
    const _Float16* Ag[4];
    const _Float16* Bg[4];
#pragma unroll
    for (int call = 0; call < 4; ++call) {
        Ag[call] = A  + (size_t)(m0 + call * 32 + r0) * EDIM + g;
        Bg[call] = Bt + (size_t)(n0 + call * 32 + r0) * EDIM + g;
    }
    _Float16* AsD = &As[tid * 8];        // call c adds c*2048 halfs
    _Float16* BsD = &Bs[tid * 8];

    // fragment read bases: row = wr*64 + i*16 + lrow (64 halfs per row)
    const int swr = lrow & 7;
    const _Float16* ardA = &As[(wr * 64 + lrow) * 64];
    const _Float16* brdB = &Bs[(wc * 64 + lrow) * 64];

    for (int k0 = 0; k0 < EDIM; k0 += 64) {
#pragma unroll
        for (int call = 0; call < 4; ++call) {
            gld_lds16(Ag[call] + k0, AsD + call * 2048);
            gld_lds16(Bg[call] + k0, BsD + call * 2048);
        }
        __syncthreads();  // drains vmcnt before s_barrier

#pragma unroll
        for (int kstep = 0; kstep < 2; ++kstep) {
            const int soff = ((kstep * 4 + lquad) ^ swr) * 8;
            half8 af[4], bf[4];
#pragma unroll
            for (int t = 0; t < 4; ++t) {
                af[t] = *(const half8*)(ardA + t * 16 * 64 + soff);
                bf[t] = *(const half8*)(brdB + t * 16 * 64 + soff);
            }
#pragma unroll
            for (int i = 0; i < 4; ++i)
#pragma unroll
                for (int j = 0; j < 4; ++j)
                    acc[i][j] = __builtin_amdgcn_mfma_f32_16x16x32_f16(
                        af[i], bf[j], acc[i][j], 0, 0, 0);
        }
        __syncthreads();  // protect LDS before next stage
    }

    // Epilogue. C/D layout (m89-verified): col = lane&15, row = (lane>>4)*4 + reg
    const int cm = m0 + wr * 64 + lquad * 4;
    const int cn = n0 + wc * 64 + lrow;
#pragma unroll
    for (int j = 0; j < 4; ++j) {
        const int gn = cn + j * 16;
        float bv;
        if (MODE == 0) {
            bv = bias[gn];
        } else {
            // gn-groups are 16-aligned and NTRI/NTRI+64 are multiples of 16,
            // so these branches are wave-subgroup-uniform.
            if (gn < NTRI)             bv = bias[gn];
            else if (gn < NTRI + VDIM) bv = bias2[gn - NTRI];
            else                       bv = 0.0f;
        }
#pragma unroll
        for (int i = 0; i < 4; ++i) {
#pragma unroll
            for (int r = 0; r < 4; ++r) {
                float x = acc[i][j][r] + bv;
                float y;
                if (MODE == 0) {
                    y = 0.5f * x * (1.0f + fast_erf(x * 0.70710678118654752f));
                } else {
                    if (gn < NTRI) {
                        y = fast_softplus(x);
                    } else if (gn < NTRI + VDIM) {
                        y = x;             // raw pi logit
                    } else {
                        y = 0.0f;          // padding
                    }
                }
                C[(size_t)(cm + i * 16 + r) * N + gn] = (_Float16)y;
            }
        }
    }
}

// ---------------- LayerNorm: fp16 G in -> fp16 Hh out (no fp32 writeback) ----
__global__ __launch_bounds__(256) void ln_kernel(const _Float16* __restrict__ G,
                                                 const float* __restrict__ gw,
                                                 const float* __restrict__ bw,
                                                 _Float16* __restrict__ Hh) {
    const int row = blockIdx.x, tid = threadIdx.x;
    half4v v = ((const half4v*)(G + (size_t)row * EDIM))[tid];
    float x0 = (float)v[0], x1 = (float)v[1], x2 = (float)v[2], x3 = (float)v[3];
    float s  = x0 + x1 + x2 + x3;
    float ss = x0 * x0 + x1 * x1 + x2 * x2 + x3 * x3;
#pragma unroll
    for (int off = 32; off; off >>= 1) {
        s  += __shfl_down(s, off);
        ss += __shfl_down(ss, off);
    }
    __shared__ float red[8];
    const int w = tid >> 6, lane = tid & 63;
    if (lane == 0) { red[w] = s; red[4 + w] = ss; }
    __syncthreads();
    const float st  = red[0] + red[1] + red[2] + red[3];
    const float sst = red[4] + red[5] + red[6] + red[7];
    const float mu  = st * (1.0f / EDIM);
    const float rs  = 1.0f / sqrtf(sst * (1.0f / EDIM) - mu * mu + 1e-5f);
    float4 gg = ((const float4*)gw)[tid];
    float4 bb = ((const float4*)bw)[tid];
    half4v h4;
    h4[0] = (_Float16)((x0 - mu) * rs * gg.x + bb.x);
    h4[1] = (_Float16)((x1 - mu) * rs * gg.y + bb.y);
    h4[2] = (_Float16)((x2 - mu) * rs * gg.z + bb.z);
    h4[3] = (_Float16)((x3 - mu) * rs * gg.w + bb.w);
    ((half4v*)(Hh + (size_t)row * EDIM))[tid] = h4;
}

// ---------------- Q build + fused softmax: one block per (b,l) row ---------
// Wave 3 computes softmax over the 64 logit columns (Theta[NTRI..NTRI+64))
// -> pi_out + sqrt(pi) in LDS, while threads 0..251 stage the 2016 Theta
// values (half8 loads, fp32 in LDS). Then:
// Q[i][j] = Theta[tri(i,j)] * sp[j]/sp[i] (i!=j), Q[i][i] = -rowsum (folded
// into the vectorized store).
__global__ __launch_bounds__(256) void q_kernel(const _Float16* __restrict__ Theta,
                                                float* __restrict__ pi_out,
                                                float* __restrict__ Q) {
    const int row = blockIdx.x;
    const int tid = threadIdx.x;
    __shared__ float Th[NTRI];
    __shared__ float spv[VDIM];
    const _Float16* trow = Theta + (size_t)row * NTC;
    if (tid < 252) {  // 252 * 8 = 2016 = NTRI exactly
        half8 h = *(const half8*)(trow + tid * 8);
#pragma unroll
        for (int u = 0; u < 8; ++u) Th[tid * 8 + u] = (float)h[u];
    }
    if (tid >= 192) {  // wave 3: softmax over the 64 logits
        const int lane = tid & 63;
        float lg = (float)trow[NTRI + lane];
        float m = lg;
#pragma unroll
        for (int off = 32; off; off >>= 1) m = fmaxf(m, __shfl_xor(m, off));
        float e = __expf(lg - m);
        float ssum = e;
#pragma unroll
        for (int off = 32; off; off >>= 1) ssum += __shfl_xor(ssum, off);
        float p = e / ssum;
        pi_out[(size_t)row * VDIM + lane] = p;
        spv[lane] = sqrtf(p);
    }
    __syncthreads();

    const int i = tid >> 2;   // Q row 0..63
    const int q = tid & 3;    // col quarter
    const float rpi = 1.0f / spv[i];
    float vals[16];
    float psum = 0.f;
#pragma unroll
    for (int c = 0; c < 16; ++c) {
        const int j = q * 16 + c;
        float out = 0.f;
        if (j != i) {
            const int a = (i < j) ? i : j;
            const int b = (i < j) ? j : i;
            const int t = a * (127 - a) / 2 + (b - a - 1);
            out = Th[t] * spv[j] * rpi;
            psum += out;
        }
        vals[c] = out;
    }
    // full rowsum across the 4 consecutive lanes of this row
    psum += __shfl_xor(psum, 1);
    psum += __shfl_xor(psum, 2);
    if ((i >> 4) == q) vals[i & 15] = -psum;   // fold diagonal into the store

    float* qrow = Q + ((size_t)row * VDIM + i) * VDIM + q * 16;
    float4* dst = (float4*)qrow;
    dst[0] = make_float4(vals[0], vals[1], vals[2], vals[3]);
    dst[1] = make_float4(vals[4], vals[5], vals[6], vals[7]);
    dst[2] = make_float4(vals[8], vals[9], vals[10], vals[11]);
    dst[3] = make_float4(vals[12], vals[13], vals[14], vals[15]);
}

// ---------------- orchestration ----------------
extern "C" void kernel_launch(void* const* d_in, const int* in_sizes, int n_in,
                              void* d_out, int out_size, void* d_ws, size_t ws_size,
                              hipStream_t stream) {
    const float* hx      = (const float*)d_in[0];
    const float* W_dense = (const float*)d_in[1];
    const float* b_dense = (const float*)d_in[2];
    const float* ln_g    = (const float*)d_in[3];
    const float* ln_b    = (const float*)d_in[4];
    const float* W_theta = (const float*)d_in[5];
    const float* b_theta = (const float*)d_in[6];
    const float* W_Theta = (const float*)d_in[7];
    const float* b_Theta = (const float*)d_in[8];

    uint8_t* ws = (uint8_t*)d_ws;
    // ws layout (~59 MB peak):
    _Float16* A_h  = (_Float16*)ws;                          // 16 MB (hx fp16; later h fp16)
    _Float16* Wd_h = (_Float16*)(ws + (size_t)16 * 1048576); //  2 MB
    _Float16* Wc_h = (_Float16*)(ws + (size_t)18 * 1048576); //  4.25 MB (2176x1024: W_Theta|W_theta|0)
    _Float16* G_h  = (_Float16*)(ws + (size_t)23 * 1048576); // 16 MB (gelu out, fp16)
    _Float16* Th_h = (_Float16*)(ws + (size_t)23 * 1048576); // 35.7 MB (8192x2176 fp16) — reuses G after LN

    float* Q_out  = (float*)d_out;                 // 8192*64*64
    float* pi_out = (float*)d_out + (size_t)MROWS * VDIM * VDIM;

    // 1) casts to fp16; combined theta weight = [W_Theta ; W_theta ; zeros]
    cast_f2h<<<(MROWS * EDIM / 4) / 256, 256, 0, stream>>>(hx, A_h, MROWS * EDIM, MROWS * EDIM);
    cast_f2h<<<(EDIM * EDIM / 4) / 256, 256, 0, stream>>>(W_dense, Wd_h, EDIM * EDIM, EDIM * EDIM);
    cast_f2h<<<(NTRI * EDIM / 4) / 256, 256, 0, stream>>>(W_Theta, Wc_h, NTRI * EDIM, NTRI * EDIM);
    cast_f2h<<<((NTC - NTRI) * EDIM / 4) / 256, 256, 0, stream>>>(
        W_theta, Wc_h + (size_t)NTRI * EDIM, VDIM * EDIM, (NTC - NTRI) * EDIM);

    // 2) dense GEMM + gelu -> G_h (fp16)  (1D grid, XCD-aware mapping inside)
    gemm_bt<0><<<(EDIM / 128) * (MROWS / 128), 256, 0, stream>>>(
        A_h, Wd_h, b_dense, nullptr, G_h, EDIM);

    // 3) LayerNorm: fp16 G -> fp16 h into A_h (hx fp16 no longer needed)
    ln_kernel<<<MROWS, 256, 0, stream>>>(G_h, ln_g, ln_b, A_h);

    // 4) combined Theta+logits GEMM (softplus / raw epilogue) -> Th_h fp16
    //    (overwrites G_h, which is dead after ln_kernel)
    gemm_bt<1><<<(NTC / 128) * (MROWS / 128), 256, 0, stream>>>(
        A_h, Wc_h, b_Theta, b_theta, Th_h, NTC);

    // 5) Q assembly + fused softmax (pi, sqrt(pi) computed in-kernel)
    q_kernel<<<MROWS, 256, 0, stream>>>(Th_h, pi_out, Q_out);
}